// Round 13
// baseline (74.789 us; speedup 1.0000x reference)
//
#include <hip/hip_runtime.h>
#include <cstddef>

#define SEQLEN 32
#define BATCH  32768
#define POSE   34
#define PREDL  15
#define LOG2E  1.4426950408889634f
#define K2E    2.8853901817779268f

typedef __attribute__((ext_vector_type(8))) short short8;
typedef __attribute__((ext_vector_type(4))) float f32x4;
typedef union { short8 s8; unsigned u[4]; } pk8;

#define MF(a,b,c) __builtin_amdgcn_mfma_f32_16x16x32_bf16(a,b,c,0,0,0)
#define EXP2(x)  __builtin_amdgcn_exp2f(x)
#define RCP(x)   __builtin_amdgcn_rcpf(x)

__device__ __forceinline__ unsigned short f2bf(float f){ __bf16 b=(__bf16)f; return __builtin_bit_cast(unsigned short,b); }
__device__ __forceinline__ unsigned f22bf(float lo,float hi){ return (unsigned)f2bf(lo) | ((unsigned)f2bf(hi)<<16); }
__device__ __forceinline__ short8 zero8(){ pk8 r; r.u[0]=0;r.u[1]=0;r.u[2]=0;r.u[3]=0; return r.s8; }
__device__ __forceinline__ float scGT(int gt){ return (gt==2)?K2E:LOG2E; }

__device__ __forceinline__ short8 g8s(const float* __restrict__ p, float s){
    pk8 r;
    r.u[0]=f22bf(p[0]*s,p[1]*s); r.u[1]=f22bf(p[2]*s,p[3]*s);
    r.u[2]=f22bf(p[4]*s,p[5]*s); r.u[3]=f22bf(p[6]*s,p[7]*s);
    return r.s8;
}

// dual-chain packed trans-reduced pointwise: both chains in one block -> the
// scheduler interleaves A/B streams, each hides the other's latency.
__device__ __forceinline__ void pw4v2(const f32x4 (&ac)[2][4], f32x4 (&cs)[2],
                                      unsigned (&hp0)[2], unsigned (&hp1)[2]){
    f32x4 A[2],C[2],B[2],O[2];
#pragma unroll
    for(int ch=0;ch<2;++ch)
#pragma unroll
    for(int j=0;j<4;++j){
        A[ch][j]=EXP2(-ac[ch][0][j]); C[ch][j]=EXP2(-ac[ch][1][j]);
        B[ch][j]=EXP2( ac[ch][2][j]); O[ch][j]=EXP2(-ac[ch][3][j]);
    }
    const f32x4 one={1.f,1.f,1.f,1.f};
#pragma unroll
    for(int ch=0;ch<2;++ch){
        f32x4 u=one+A[ch], w=one+C[ch], v=B[ch]+one, Bm=B[ch]-one;
        f32x4 t1=u*v;
        f32x4 num=cs[ch]*t1+Bm*w;
        f32x4 den=t1*w;
        f32x4 rd_,E,rh;
#pragma unroll
        for(int j=0;j<4;++j) rd_[j]=RCP(den[j]);
        f32x4 cn=num*rd_;
        cs[ch]=cn;
#pragma unroll
        for(int j=0;j<4;++j) E[j]=EXP2(K2E*cn[j]);
        f32x4 hd=(one+O[ch])*(E+one);
#pragma unroll
        for(int j=0;j<4;++j) rh[j]=RCP(hd[j]);
        f32x4 hv=(E-one)*rh;
        hp0[ch]=f22bf(hv[0],hv[1]); hp1[ch]=f22bf(hv[2],hv[3]);
    }
}

// ---- prep: fold decoder/crossing weights, pre-scaled, into workspace ----
extern "C" __global__ void lstm_prep(
    const float* __restrict__ dWih, const float* __restrict__ dWhh,
    const float* __restrict__ dbih, const float* __restrict__ dbhh,
    const float* __restrict__ cWih, const float* __restrict__ cWhh,
    const float* __restrict__ cbih, const float* __restrict__ cbhh,
    const float* __restrict__ fcW,  const float* __restrict__ fcb,
    const float* __restrict__ embW, const float* __restrict__ embb,
    float* __restrict__ wsBD, float* __restrict__ wsBC,
    unsigned short* __restrict__ wsDh, unsigned short* __restrict__ wsCh,
    unsigned short* __restrict__ wsCp)
{
    int idx = blockIdx.x*256 + threadIdx.x;
    if(idx < 1024){
        int R=idx>>4, k=idx&15;
        float s=scGT(R>>4);
        float vD=dWhh[R*16+k];
        for(int p=0;p<34;++p) vD=fmaf(dWih[R*34+p],fcW[p*16+k],vD);
        wsDh[idx]=f2bf(vD*s);
        wsCh[idx]=f2bf(cWhh[R*16+k]*s);
    }
    if(idx < 128){
        int R=idx>>1, k=idx&1;
        float s=scGT(R>>4);
        float v=0.f;
        for(int p=0;p<34;++p) v=fmaf(cWih[R*34+p],embW[2*p+k],v);
        wsCp[idx]=f2bf(v*s);
    }
    if(idx < 64){
        int R=idx;
        float s=scGT(R>>4);
        float vD=dbih[R]+dbhh[R], vC=cbih[R]+cbhh[R];
        for(int p=0;p<34;++p){ vD=fmaf(dWih[R*34+p],fcb[p],vD); vC=fmaf(cWih[R*34+p],embb[p],vC); }
        wsBD[idx]=vD*s; wsBC[idx]=vC*s;
    }
}

// two independent 16-batch chains per wave; 1 wave/SIMD; SW-interleaved.
extern "C" __global__ void __launch_bounds__(256,1) lstm_w8(
    const float* __restrict__ obs_s,
    const float* __restrict__ eWih, const float* __restrict__ eWhh,
    const float* __restrict__ ebih, const float* __restrict__ ebhh,
    const float* __restrict__ dWih, const float* __restrict__ dWhh,
    const float* __restrict__ dbih, const float* __restrict__ dbhh,
    const float* __restrict__ cWih, const float* __restrict__ cWhh,
    const float* __restrict__ cbih, const float* __restrict__ cbhh,
    const float* __restrict__ fcW,  const float* __restrict__ fcb,
    const float* __restrict__ fccW, const float* __restrict__ fccb,
    const float* __restrict__ mlpW, const float* __restrict__ mlpb,
    const float* __restrict__ wsBD, const float* __restrict__ wsBC,
    const unsigned short* __restrict__ wsDh, const unsigned short* __restrict__ wsCh,
    const unsigned short* __restrict__ wsCp,
    float* __restrict__ out_s, float* __restrict__ out_cr)
{
    __shared__ unsigned xt4[4][2][2][320];   // [wave][chain][step-slot][16 rows x 20 words]

    const int tid=threadIdx.x;
    const int l=tid&63;
    const int wv=tid>>6;
    const int lo=l&15, g=l>>4;
    const int pb=blockIdx.x*128 + wv*32;     // chain ch covers pb+16*ch .. +16
    unsigned (*XT)[2][320]=xt4[wv];

    unsigned pofs[5]; int wofs[5];
#pragma unroll
    for(int it=0; it<5; ++it){
        int i2=l+64*it;
        int r=i2/17, w=i2-r*17;
        pofs[it]=(unsigned)((pb+r)*17+w);
        wofs[it]=r*20+w;
    }

    // ---- encoder weights (shared by both chains) ----
    short8 wEx[4], wEhT[4]; f32x4 biasE[4];
#pragma unroll
    for(int gt=0;gt<4;++gt){
        float s=scGT(gt);
        int R=gt*16+lo;
        wEx[gt]=g8s(&eWih[R*34+8*g], s);
        pk8 r2;
        r2.u[0]=f22bf(eWhh[R*16+4*g]*s,   eWhh[R*16+4*g+1]*s);
        r2.u[1]=f22bf(eWhh[R*16+4*g+2]*s, eWhh[R*16+4*g+3]*s);
        r2.u[2]=(g==0)? f22bf(eWih[R*34+32]*s, eWih[R*34+33]*s) : 0u;
        r2.u[3]=0u;
        wEhT[gt]=r2.s8;
        float4 ba=*(const float4*)&ebih[gt*16+4*g];
        float4 bb=*(const float4*)&ebhh[gt*16+4*g];
        biasE[gt]=f32x4{(ba.x+bb.x)*s,(ba.y+bb.y)*s,(ba.z+bb.z)*s,(ba.w+bb.w)*s};
    }

    f32x4 cS[2]={{0.f,0.f,0.f,0.f},{0.f,0.f,0.f,0.f}};
    unsigned hp0[2]={0u,0u}, hp1[2]={0u,0u};

    float2 RA[2][2][5];                       // [chain][step-slot][5]
    auto ldblk=[&](int t0){
#pragma unroll
        for(int s2=0;s2<2;++s2){
            const float2* base=(const float2*)obs_s + (size_t)(t0+s2)*(BATCH*17);
#pragma unroll
            for(int ch=0;ch<2;++ch)
#pragma unroll
            for(int it=0;it<5;++it)
                if(it<4 || l<16) RA[ch][s2][it]=base[pofs[it]+ch*272u];
        }
    };
    auto wrblk=[&](){
#pragma unroll
        for(int ch=0;ch<2;++ch)
#pragma unroll
        for(int s2=0;s2<2;++s2)
#pragma unroll
        for(int it=0;it<5;++it)
            if(it<4 || l<16) XT[ch][s2][wofs[it]]=f22bf(RA[ch][s2][it].x,RA[ch][s2][it].y);
    };

    // ---- encoder: 16 rolled blocks of 2 steps, dual chains interleaved ----
    short8 fbQ[2]; unsigned ftQ[2];
    fbQ[0]=zero8(); fbQ[1]=zero8(); ftQ[0]=0u; ftQ[1]=0u;
    ldblk(0);
#pragma unroll 1
    for(int kb=0;kb<16;++kb){
        wrblk();
        if(kb+1<16) ldblk(2*(kb+1));
        short8 bx[2][2]; unsigned tw[2][2];
#pragma unroll
        for(int ch=0;ch<2;++ch)
#pragma unroll
        for(int s2=0;s2<2;++s2){
            bx[ch][s2]=*(const short8*)&XT[ch][s2][lo*20+4*g];
            tw[ch][s2]=XT[ch][s2][lo*20+16];
        }
        f32x4 cx[2][2][4];
#pragma unroll
        for(int ch=0;ch<2;++ch)
#pragma unroll
        for(int s2=0;s2<2;++s2)
#pragma unroll
        for(int gt=0;gt<4;++gt)
            cx[ch][s2][gt]=MF(wEx[gt],bx[ch][s2],biasE[gt]);   // off-chain
        fbQ[0]=bx[0][1]; ftQ[0]=tw[0][1];
        fbQ[1]=bx[1][1]; ftQ[1]=tw[1][1];
#pragma unroll
        for(int s2=0;s2<2;++s2){
            f32x4 acc[2][4];
#pragma unroll
            for(int ch=0;ch<2;++ch){
                pk8 bh; bh.u[0]=hp0[ch]; bh.u[1]=hp1[ch];
                bh.u[2]=(g==0)?tw[ch][s2]:0u; bh.u[3]=0u;
#pragma unroll
                for(int gt=0;gt<4;++gt) acc[ch][gt]=MF(wEhT[gt],bh.s8,cx[ch][s2][gt]);
            }
            pw4v2(acc,cS,hp0,hp1);
        }
    }

    // ---- decoder weights -> VGPRs (shared) ----
    short8 wDh[4], wCA[4]; f32x4 biasD[4], biasC[4];
#pragma unroll
    for(int gt=0;gt<4;++gt){
        int R=gt*16+lo;
        uint2 qd=*(const uint2*)&wsDh[R*16+4*g];
        pk8 rd; rd.u[0]=qd.x; rd.u[1]=qd.y; rd.u[2]=0u; rd.u[3]=0u;
        wDh[gt]=rd.s8;
        uint2 qc=*(const uint2*)&wsCh[R*16+4*g];
        pk8 rc; rc.u[0]=qc.x; rc.u[1]=qc.y;
        rc.u[2]=(g==0)? *(const unsigned*)&wsCp[R*2] : 0u; rc.u[3]=0u;
        wCA[gt]=rc.s8;
        biasD[gt]=*(const f32x4*)&wsBD[gt*16+4*g];
        biasC[gt]=*(const f32x4*)&wsBC[gt*16+4*g];
    }
    short8 wF[3]; f32x4 fcbF[3];
#pragma unroll
    for(int nt=0;nt<3;++nt){
        int np=nt*16+lo;
        if(np<POSE){
            pk8 r;
            r.u[0]=f22bf(fcW[np*16+4*g],   fcW[np*16+4*g+1]);
            r.u[1]=f22bf(fcW[np*16+4*g+2], fcW[np*16+4*g+3]);
            r.u[2]=0u; r.u[3]=0u;
            wF[nt]=r.s8;
        } else wF[nt]=zero8();
#pragma unroll
        for(int j=0;j<4;++j){
            int row=nt*16+4*g+j;
            fcbF[nt][j]=(row<POSE)? fcb[row] : 0.f;
        }
    }
    short8 wFC, wM; f32x4 fccC, mlpbF;
    if(lo<2){
        pk8 r;
        r.u[0]=f22bf(fccW[lo*16+4*g],   fccW[lo*16+4*g+1]);
        r.u[1]=f22bf(fccW[lo*16+4*g+2], fccW[lo*16+4*g+3]);
        r.u[2]=0u; r.u[3]=0u; wFC=r.s8;
    } else wFC=zero8();
    fccC=(g==0)? f32x4{fccb[0],fccb[1],0.f,0.f} : f32x4{0.f,0.f,0.f,0.f};
    {
        pk8 r;
        r.u[0]=f22bf(mlpW[lo*16+4*g],   mlpW[lo*16+4*g+1]);
        r.u[1]=f22bf(mlpW[lo*16+4*g+2], mlpW[lo*16+4*g+3]);
        r.u[2]=0u; r.u[3]=0u; wM=r.s8;
        mlpbF=*(const f32x4*)&mlpb[4*g];
    }

    // hc = mlp(h_enc) per chain
    unsigned hcp0[2],hcp1[2];
#pragma unroll
    for(int ch=0;ch<2;++ch){
        pk8 bh; bh.u[0]=hp0[ch]; bh.u[1]=hp1[ch]; bh.u[2]=0u; bh.u[3]=0u;
        f32x4 o=MF(wM,bh.s8,mlpbF);
        hcp0[ch]=f22bf(o[0],o[1]); hcp1[ch]=f22bf(o[2],o[3]);
    }
    f32x4 cC[2]={{0.f,0.f,0.f,0.f},{0.f,0.f,0.f,0.f}};
    unsigned pp[2]={0u,0u};

    auto dec_tail=[&](int s, const f32x4 (&aC)[2][4], const f32x4 (&aD)[2][4]){
        pw4v2(aD,cS,hp0,hp1);
        pw4v2(aC,cC,hcp0,hcp1);
#pragma unroll
        for(int ch=0;ch<2;++ch){
            const int pbc=pb+16*ch;
            pk8 bhc; bhc.u[0]=hcp0[ch]; bhc.u[1]=hcp1[ch]; bhc.u[2]=0u; bhc.u[3]=0u;
            f32x4 zz=MF(wFC,bhc.s8,fccC);
            float z0=zz[0], z1=zz[1];
            float mx=fmaxf(z0,z1);
            float e0=EXP2(LOG2E*(z0-mx)), e1=EXP2(LOG2E*(z1-mx));
            float rs=RCP(e0+e1);
            float p0=e0*rs, p1=e1*rs;
            unsigned ppn=f22bf(p0,p1);
            if(g==0)
                ((float2*)out_cr)[(size_t)s*BATCH+pbc+lo]=make_float2(p0,p1);
            pp[ch]=(unsigned)__shfl((int)ppn, lo, 64);
            pk8 bh; bh.u[0]=hp0[ch]; bh.u[1]=hp1[ch]; bh.u[2]=0u; bh.u[3]=0u;
            float* po = out_s + ((size_t)s*BATCH + pbc + lo)*POSE;
            f32x4 o0=MF(wF[0],bh.s8,fcbF[0]);
            f32x4 o1=MF(wF[1],bh.s8,fcbF[1]);
            *(float2*)(po+4*g)     =make_float2(o0[0],o0[1]);
            *(float2*)(po+4*g+2)   =make_float2(o0[2],o0[3]);
            *(float2*)(po+16+4*g)  =make_float2(o1[0],o1[1]);
            *(float2*)(po+16+4*g+2)=make_float2(o1[2],o1[3]);
            f32x4 o2=MF(wF[2],bh.s8,fcbF[2]);
            if(g==0) *(float2*)(po+32)=make_float2(o2[0],o2[1]);
        }
    };

    // ---- s=0 (peeled: original weights gathered ONCE, shared by chains) ----
    {
        short8 a1c[4],a2c[4],a1d[4],a2d[4]; f32x4 bc0[4],bd0[4];
#pragma unroll
        for(int gt=0;gt<4;++gt){
            float sgt=scGT(gt);
            int R=gt*16+lo;
            a1c[gt]=g8s(&cWih[R*34+8*g], sgt);
            pk8 a2;
            a2.u[0]=f22bf(cWhh[R*16+4*g]*sgt,   cWhh[R*16+4*g+1]*sgt);
            a2.u[1]=f22bf(cWhh[R*16+4*g+2]*sgt, cWhh[R*16+4*g+3]*sgt);
            a2.u[2]=(g==0)? f22bf(cWih[R*34+32]*sgt, cWih[R*34+33]*sgt) : 0u;
            a2.u[3]=0u;
            a2c[gt]=a2.s8;
            float4 ba=*(const float4*)&cbih[gt*16+4*g];
            float4 bb=*(const float4*)&cbhh[gt*16+4*g];
            bc0[gt]=f32x4{(ba.x+bb.x)*sgt,(ba.y+bb.y)*sgt,(ba.z+bb.z)*sgt,(ba.w+bb.w)*sgt};
            a1d[gt]=g8s(&dWih[R*34+8*g], sgt);
            pk8 d2;
            d2.u[0]=f22bf(dWhh[R*16+4*g]*sgt,   dWhh[R*16+4*g+1]*sgt);
            d2.u[1]=f22bf(dWhh[R*16+4*g+2]*sgt, dWhh[R*16+4*g+3]*sgt);
            d2.u[2]=(g==0)? f22bf(dWih[R*34+32]*sgt, dWih[R*34+33]*sgt) : 0u;
            d2.u[3]=0u;
            a2d[gt]=d2.s8;
            float4 da=*(const float4*)&dbih[gt*16+4*g];
            float4 db=*(const float4*)&dbhh[gt*16+4*g];
            bd0[gt]=f32x4{(da.x+db.x)*sgt,(da.y+db.y)*sgt,(da.z+db.z)*sgt,(da.w+db.w)*sgt};
        }
        f32x4 aC[2][4], aD[2][4];
#pragma unroll
        for(int ch=0;ch<2;++ch){
            pk8 bhc; bhc.u[0]=hcp0[ch]; bhc.u[1]=hcp1[ch];
            bhc.u[2]=(g==0)?ftQ[ch]:0u; bhc.u[3]=0u;
            pk8 bhd; bhd.u[0]=hp0[ch]; bhd.u[1]=hp1[ch];
            bhd.u[2]=(g==0)?ftQ[ch]:0u; bhd.u[3]=0u;
#pragma unroll
            for(int gt=0;gt<4;++gt){
                f32x4 cxx=MF(a1c[gt],fbQ[ch],bc0[gt]);
                aC[ch][gt]=MF(a2c[gt],bhc.s8,cxx);
                f32x4 dxx=MF(a1d[gt],fbQ[ch],bd0[gt]);
                aD[ch][gt]=MF(a2d[gt],bhd.s8,dxx);
            }
        }
        dec_tail(0,aC,aD);
    }
    // ---- s=1..14: folded cells, dual chains, pure-register ----
#pragma unroll 1
    for(int s=1;s<PREDL;++s){
        f32x4 aC[2][4], aD[2][4];
#pragma unroll
        for(int ch=0;ch<2;++ch){
            pk8 bd; bd.u[0]=hp0[ch]; bd.u[1]=hp1[ch]; bd.u[2]=0u; bd.u[3]=0u;
            pk8 bc; bc.u[0]=hcp0[ch]; bc.u[1]=hcp1[ch];
            bc.u[2]=(g==0)?pp[ch]:0u; bc.u[3]=0u;
#pragma unroll
            for(int gt=0;gt<4;++gt){
                aD[ch][gt]=MF(wDh[gt],bd.s8,biasD[gt]);
                aC[ch][gt]=MF(wCA[gt],bc.s8,biasC[gt]);
            }
        }
        dec_tail(s,aC,aD);
    }
}

extern "C" void kernel_launch(void* const* d_in, const int* in_sizes, int n_in,
                              void* d_out, int out_size, void* d_ws, size_t ws_size,
                              hipStream_t stream)
{
    const float* obs  = (const float*)d_in[0];
    const float* eWih = (const float*)d_in[1];
    const float* eWhh = (const float*)d_in[2];
    const float* ebih = (const float*)d_in[3];
    const float* ebhh = (const float*)d_in[4];
    const float* dWih = (const float*)d_in[5];
    const float* dWhh = (const float*)d_in[6];
    const float* dbih = (const float*)d_in[7];
    const float* dbhh = (const float*)d_in[8];
    const float* cWih = (const float*)d_in[9];
    const float* cWhh = (const float*)d_in[10];
    const float* cbih = (const float*)d_in[11];
    const float* cbhh = (const float*)d_in[12];
    const float* fcW  = (const float*)d_in[13];
    const float* fcb  = (const float*)d_in[14];
    const float* fccW = (const float*)d_in[15];
    const float* fccb = (const float*)d_in[16];
    const float* mlpW = (const float*)d_in[17];
    const float* mlpb = (const float*)d_in[18];
    const float* embW = (const float*)d_in[19];
    const float* embb = (const float*)d_in[20];

    float* out_s  = (float*)d_out;
    float* out_cr = out_s + (size_t)PREDL*BATCH*POSE;

    float* wsBD = (float*)d_ws;
    float* wsBC = wsBD + 64;
    unsigned short* wsDh = (unsigned short*)(wsBC+64);
    unsigned short* wsCh = wsDh + 1024;
    unsigned short* wsCp = wsCh + 1024;

    hipLaunchKernelGGL(lstm_prep, dim3(4), dim3(256), 0, stream,
                       dWih, dWhh, dbih, dbhh, cWih, cWhh, cbih, cbhh,
                       fcW, fcb, embW, embb, wsBD, wsBC, wsDh, wsCh, wsCp);
    hipLaunchKernelGGL(lstm_w8, dim3(BATCH/128), dim3(256), 0, stream,
                       obs, eWih, eWhh, ebih, ebhh, dWih, dWhh, dbih, dbhh,
                       cWih, cWhh, cbih, cbhh, fcW, fcb, fccW, fccb,
                       mlpW, mlpb, wsBD, wsBC, wsDh, wsCh, wsCp,
                       out_s, out_cr);
}

// Round 14
// 65.451 us; speedup vs baseline: 1.1427x; 1.1427x over previous
//
#include <hip/hip_runtime.h>
#include <cstddef>

#define SEQLEN 32
#define BATCH  32768
#define POSE   34
#define PREDL  15
#define LOG2E  1.4426950408889634f
#define K2E    2.8853901817779268f

typedef __attribute__((ext_vector_type(8))) short short8;
typedef __attribute__((ext_vector_type(4))) float f32x4;
typedef union { short8 s8; unsigned u[4]; } pk8;

#define MF(a,b,c) __builtin_amdgcn_mfma_f32_16x16x32_bf16(a,b,c,0,0,0)
#define EXP2(x)  __builtin_amdgcn_exp2f(x)
#define RCP(x)   __builtin_amdgcn_rcpf(x)

__device__ __forceinline__ unsigned short f2bf(float f){ __bf16 b=(__bf16)f; return __builtin_bit_cast(unsigned short,b); }
__device__ __forceinline__ unsigned f22bf(float lo,float hi){ return (unsigned)f2bf(lo) | ((unsigned)f2bf(hi)<<16); }
__device__ __forceinline__ short8 zero8(){ pk8 r; r.u[0]=0;r.u[1]=0;r.u[2]=0;r.u[3]=0; return r.s8; }
__device__ __forceinline__ float scGT(int gt){ return (gt==2)?K2E:LOG2E; }

__device__ __forceinline__ short8 g8s(const float* __restrict__ p, float s){
    pk8 r;
    r.u[0]=f22bf(p[0]*s,p[1]*s); r.u[1]=f22bf(p[2]*s,p[3]*s);
    r.u[2]=f22bf(p[4]*s,p[5]*s); r.u[3]=f22bf(p[6]*s,p[7]*s);
    return r.s8;
}

// packed trans-reduced pointwise (identical numerics to R10)
__device__ __forceinline__ void pw4v(const f32x4 (&ac)[4], f32x4 &cs,
                                     unsigned &hp0, unsigned &hp1){
    f32x4 A,C,B,O;
#pragma unroll
    for(int j=0;j<4;++j){
        A[j]=EXP2(-ac[0][j]); C[j]=EXP2(-ac[1][j]);
        B[j]=EXP2( ac[2][j]); O[j]=EXP2(-ac[3][j]);
    }
    const f32x4 one={1.f,1.f,1.f,1.f};
    f32x4 u=one+A, w=one+C, v=B+one, Bm=B-one;
    f32x4 t1=u*v;
    f32x4 num=cs*t1+Bm*w;
    f32x4 den=t1*w;
    f32x4 rd_,E,rh;
#pragma unroll
    for(int j=0;j<4;++j) rd_[j]=RCP(den[j]);
    f32x4 cn=num*rd_;
    cs=cn;
#pragma unroll
    for(int j=0;j<4;++j) E[j]=EXP2(K2E*cn[j]);
    f32x4 hd=(one+O)*(E+one);
#pragma unroll
    for(int j=0;j<4;++j) rh[j]=RCP(hd[j]);
    f32x4 hv=(E-one)*rh;
    hp0=f22bf(hv[0],hv[1]); hp1=f22bf(hv[2],hv[3]);
}

// ---------------- kernel1: encoder + mlp + handoff; block 512 = fold prep ----
extern "C" __global__ void __launch_bounds__(256,2) lstm_enc(
    const float* __restrict__ obs_s,
    const float* __restrict__ eWih, const float* __restrict__ eWhh,
    const float* __restrict__ ebih, const float* __restrict__ ebhh,
    const float* __restrict__ mlpW, const float* __restrict__ mlpb,
    const float* __restrict__ dWih, const float* __restrict__ dWhh,
    const float* __restrict__ dbih, const float* __restrict__ dbhh,
    const float* __restrict__ cWih, const float* __restrict__ cWhh,
    const float* __restrict__ cbih, const float* __restrict__ cbhh,
    const float* __restrict__ fcW,  const float* __restrict__ fcb,
    const float* __restrict__ embW, const float* __restrict__ embb,
    float* __restrict__ wsBD, float* __restrict__ wsBC,
    unsigned short* __restrict__ wsDh, unsigned short* __restrict__ wsCh,
    unsigned short* __restrict__ wsCp, unsigned* __restrict__ hand)
{
    __shared__ unsigned xt4[4][4][320];

    if(blockIdx.x>=512){                 // ---- fold-prep block (overlaps encoder) ----
        for(int idx=threadIdx.x; idx<1024; idx+=256){
            int R=idx>>4, k=idx&15;
            float s=scGT(R>>4);
            float vD=dWhh[R*16+k];
            for(int p=0;p<34;++p) vD=fmaf(dWih[R*34+p],fcW[p*16+k],vD);
            wsDh[idx]=f2bf(vD*s);
            wsCh[idx]=f2bf(cWhh[R*16+k]*s);
        }
        for(int idx=threadIdx.x; idx<128; idx+=256){
            int R=idx>>1, k=idx&1;
            float s=scGT(R>>4);
            float v=0.f;
            for(int p=0;p<34;++p) v=fmaf(cWih[R*34+p],embW[2*p+k],v);
            wsCp[idx]=f2bf(v*s);
        }
        for(int idx=threadIdx.x; idx<64; idx+=256){
            int R=idx;
            float s=scGT(R>>4);
            float vD=dbih[R]+dbhh[R], vC=cbih[R]+cbhh[R];
            for(int p=0;p<34;++p){ vD=fmaf(dWih[R*34+p],fcb[p],vD); vC=fmaf(cWih[R*34+p],embb[p],vC); }
            wsBD[idx]=vD*s; wsBC[idx]=vC*s;
        }
        return;
    }

    const int tid=threadIdx.x;
    const int l=tid&63;
    const int wv=tid>>6;
    const int lo=l&15, g=l>>4;
    const int pb=blockIdx.x*64 + wv*16;
    unsigned* XT=&xt4[wv][0][0];

    unsigned pofs[5]; int wofs[5];
#pragma unroll
    for(int it=0; it<5; ++it){
        int i2=l+64*it;
        int r=i2/17, w=i2-r*17;
        pofs[it]=(unsigned)((pb+r)*17+w);
        wofs[it]=r*20+w;
    }

    short8 wEx[4], wEhT[4]; f32x4 biasE[4];
#pragma unroll
    for(int gt=0;gt<4;++gt){
        float s=scGT(gt);
        int R=gt*16+lo;
        wEx[gt]=g8s(&eWih[R*34+8*g], s);
        pk8 r2;
        r2.u[0]=f22bf(eWhh[R*16+4*g]*s,   eWhh[R*16+4*g+1]*s);
        r2.u[1]=f22bf(eWhh[R*16+4*g+2]*s, eWhh[R*16+4*g+3]*s);
        r2.u[2]=(g==0)? f22bf(eWih[R*34+32]*s, eWih[R*34+33]*s) : 0u;
        r2.u[3]=0u;
        wEhT[gt]=r2.s8;
        float4 ba=*(const float4*)&ebih[gt*16+4*g];
        float4 bb=*(const float4*)&ebhh[gt*16+4*g];
        biasE[gt]=f32x4{(ba.x+bb.x)*s,(ba.y+bb.y)*s,(ba.z+bb.z)*s,(ba.w+bb.w)*s};
    }

    f32x4 cS={0.f,0.f,0.f,0.f};
    unsigned hp0=0u, hp1=0u;

    float2 RA[4][5];
    auto ldblk=[&](int t0){
#pragma unroll
        for(int s=0;s<4;++s){
            const float2* base=(const float2*)obs_s + (size_t)(t0+s)*(BATCH*17);
#pragma unroll
            for(int it=0;it<5;++it)
                if(it<4 || l<16) RA[s][it]=base[pofs[it]];
        }
    };
    auto wrblk=[&](){
#pragma unroll
        for(int s=0;s<4;++s)
#pragma unroll
            for(int it=0;it<5;++it)
                if(it<4 || l<16) XT[s*320+wofs[it]]=f22bf(RA[s][it].x,RA[s][it].y);
    };

    ldblk(0);
#pragma unroll 1
    for(int kb=0;kb<8;++kb){
        wrblk();
        if(kb+1<8) ldblk(4*(kb+1));
        short8 bx[4]; unsigned tw[4];
#pragma unroll
        for(int s=0;s<4;++s){
            bx[s]=*(const short8*)&XT[s*320+lo*20+4*g];
            tw[s]=XT[s*320+lo*20+16];
        }
        f32x4 cx[4][4];
#pragma unroll
        for(int s=0;s<4;++s)
#pragma unroll
            for(int gt=0;gt<4;++gt)
                cx[s][gt]=MF(wEx[gt],bx[s],biasE[gt]);
#pragma unroll
        for(int s=0;s<4;++s){
            pk8 bh; bh.u[0]=hp0; bh.u[1]=hp1; bh.u[2]=(g==0)?tw[s]:0u; bh.u[3]=0u;
            f32x4 acc[4];
#pragma unroll
            for(int gt=0;gt<4;++gt) acc[gt]=MF(wEhT[gt],bh.s8,cx[s][gt]);
            pw4v(acc,cS,hp0,hp1);
        }
    }

    // hc0 = mlp(h_enc) + mlpb
    unsigned hcp0,hcp1;
    {
        pk8 r;
        r.u[0]=f22bf(mlpW[lo*16+4*g],   mlpW[lo*16+4*g+1]);
        r.u[1]=f22bf(mlpW[lo*16+4*g+2], mlpW[lo*16+4*g+3]);
        r.u[2]=0u; r.u[3]=0u;
        f32x4 mb=*(const f32x4*)&mlpb[4*g];
        pk8 bh; bh.u[0]=hp0; bh.u[1]=hp1; bh.u[2]=0u; bh.u[3]=0u;
        f32x4 o=MF(r.s8,bh.s8,mb);
        hcp0=f22bf(o[0],o[1]); hcp1=f22bf(o[2],o[3]);
    }

    // handoff: 8 u32 per lane
    unsigned* Hw = hand + ((size_t)(blockIdx.x*4+wv)*64 + l)*8;
    Hw[0]=hp0; Hw[1]=hp1; Hw[2]=hcp0; Hw[3]=hcp1;
    *(f32x4*)(Hw+4)=cS;
}

// ---------------- kernel2: role-specialized decoder (4 waves/SIMD) ----------
extern "C" __global__ void __launch_bounds__(256,2) lstm_dec(
    const float* __restrict__ obs_s,
    const float* __restrict__ dWih, const float* __restrict__ dWhh,
    const float* __restrict__ dbih, const float* __restrict__ dbhh,
    const float* __restrict__ cWih, const float* __restrict__ cWhh,
    const float* __restrict__ cbih, const float* __restrict__ cbhh,
    const float* __restrict__ fcW,  const float* __restrict__ fcb,
    const float* __restrict__ fccW, const float* __restrict__ fccb,
    const float* __restrict__ wsBD, const float* __restrict__ wsBC,
    const unsigned short* __restrict__ wsDh, const unsigned short* __restrict__ wsCh,
    const unsigned short* __restrict__ wsCp, const unsigned* __restrict__ hand,
    float* __restrict__ out_s, float* __restrict__ out_cr)
{
    const int tid=threadIdx.x;
    const int l=tid&63;
    const int wv=tid>>6;
    const int lo=l&15, g=l>>4;
    const int grp=blockIdx.x*2+(wv>>1);
    const int role=__builtin_amdgcn_readfirstlane(wv&1);   // 0=decoder chain, 1=crossing chain
    const int pb=grp*16;

    const unsigned* H = hand + ((size_t)grp*64 + l)*8;
    unsigned h0w=H[0], h1w=H[1], hc0w=H[2], hc1w=H[3];
    f32x4 csIn=*(const f32x4*)(H+4);

    // obs[-1] fragment (reloaded, L3-hot)
    const float* px=obs_s+((size_t)(SEQLEN-1)*BATCH+pb+lo)*POSE;
    short8 fbQ;
    {
        const float2* p2=(const float2*)(px+8*g);
        float2 q0=p2[0],q1=p2[1],q2=p2[2],q3=p2[3];
        pk8 r;
        r.u[0]=f22bf(q0.x,q0.y); r.u[1]=f22bf(q1.x,q1.y);
        r.u[2]=f22bf(q2.x,q2.y); r.u[3]=f22bf(q3.x,q3.y);
        fbQ=r.s8;
    }
    unsigned ftQ=f22bf(px[32],px[33]);

    if(role==0){
        // =========== decoder chain: h,c -> out_s ===========
        f32x4 cS=csIn;
        unsigned hp0=h0w, hp1=h1w;
        f32x4 aD[4];
        {   // s=0: original K=64 weights (pre-scaled on gather)
#pragma unroll
            for(int gt=0;gt<4;++gt){
                float s=scGT(gt);
                int R=gt*16+lo;
                short8 d1=g8s(&dWih[R*34+8*g], s);
                pk8 d2;
                d2.u[0]=f22bf(dWhh[R*16+4*g]*s,   dWhh[R*16+4*g+1]*s);
                d2.u[1]=f22bf(dWhh[R*16+4*g+2]*s, dWhh[R*16+4*g+3]*s);
                d2.u[2]=(g==0)? f22bf(dWih[R*34+32]*s, dWih[R*34+33]*s) : 0u;
                d2.u[3]=0u;
                float4 da=*(const float4*)&dbih[gt*16+4*g];
                float4 db=*(const float4*)&dbhh[gt*16+4*g];
                f32x4 bd0={(da.x+db.x)*s,(da.y+db.y)*s,(da.z+db.z)*s,(da.w+db.w)*s};
                pk8 bhd; bhd.u[0]=hp0; bhd.u[1]=hp1; bhd.u[2]=(g==0)?ftQ:0u; bhd.u[3]=0u;
                f32x4 dx=MF(d1,fbQ,bd0);
                aD[gt]=MF(d2.s8,bhd.s8,dx);
            }
        }
        // head + folded weights
        short8 wF[3]; f32x4 fcbF[3];
#pragma unroll
        for(int nt=0;nt<3;++nt){
            int np=nt*16+lo;
            if(np<POSE){
                pk8 r;
                r.u[0]=f22bf(fcW[np*16+4*g],   fcW[np*16+4*g+1]);
                r.u[1]=f22bf(fcW[np*16+4*g+2], fcW[np*16+4*g+3]);
                r.u[2]=0u; r.u[3]=0u;
                wF[nt]=r.s8;
            } else wF[nt]=zero8();
#pragma unroll
            for(int j=0;j<4;++j){
                int row=nt*16+4*g+j;
                fcbF[nt][j]=(row<POSE)? fcb[row] : 0.f;
            }
        }
        short8 wDh[4]; f32x4 biasD[4];
#pragma unroll
        for(int gt=0;gt<4;++gt){
            int R=gt*16+lo;
            uint2 qd=*(const uint2*)&wsDh[R*16+4*g];
            pk8 rd; rd.u[0]=qd.x; rd.u[1]=qd.y; rd.u[2]=0u; rd.u[3]=0u;
            wDh[gt]=rd.s8;
            biasD[gt]=*(const f32x4*)&wsBD[gt*16+4*g];
        }
#pragma unroll 1
        for(int s=0;s<PREDL;++s){
            pw4v(aD,cS,hp0,hp1);
            pk8 bh; bh.u[0]=hp0; bh.u[1]=hp1; bh.u[2]=0u; bh.u[3]=0u;
            f32x4 o0=MF(wF[0],bh.s8,fcbF[0]);
            f32x4 o1=MF(wF[1],bh.s8,fcbF[1]);
            f32x4 o2=MF(wF[2],bh.s8,fcbF[2]);
            float* po = out_s + ((size_t)s*BATCH + pb + lo)*POSE;
            *(float2*)(po+4*g)     =make_float2(o0[0],o0[1]);
            *(float2*)(po+4*g+2)   =make_float2(o0[2],o0[3]);
            *(float2*)(po+16+4*g)  =make_float2(o1[0],o1[1]);
            *(float2*)(po+16+4*g+2)=make_float2(o1[2],o1[3]);
            if(g==0) *(float2*)(po+32)=make_float2(o2[0],o2[1]);
            if(s+1<PREDL){
#pragma unroll
                for(int gt=0;gt<4;++gt) aD[gt]=MF(wDh[gt],bh.s8,biasD[gt]);
            }
        }
    } else {
        // =========== crossing chain: hc,cc,p -> out_cr ===========
        f32x4 cC={0.f,0.f,0.f,0.f};
        unsigned hcp0=hc0w, hcp1=hc1w, pp=0u;
        f32x4 aC[4];
        {   // s=0: original K=64 weights
#pragma unroll
            for(int gt=0;gt<4;++gt){
                float s=scGT(gt);
                int R=gt*16+lo;
                short8 a1=g8s(&cWih[R*34+8*g], s);
                pk8 a2;
                a2.u[0]=f22bf(cWhh[R*16+4*g]*s,   cWhh[R*16+4*g+1]*s);
                a2.u[1]=f22bf(cWhh[R*16+4*g+2]*s, cWhh[R*16+4*g+3]*s);
                a2.u[2]=(g==0)? f22bf(cWih[R*34+32]*s, cWih[R*34+33]*s) : 0u;
                a2.u[3]=0u;
                float4 ba=*(const float4*)&cbih[gt*16+4*g];
                float4 bb=*(const float4*)&cbhh[gt*16+4*g];
                f32x4 bc0={(ba.x+bb.x)*s,(ba.y+bb.y)*s,(ba.z+bb.z)*s,(ba.w+bb.w)*s};
                pk8 bhc; bhc.u[0]=hcp0; bhc.u[1]=hcp1; bhc.u[2]=(g==0)?ftQ:0u; bhc.u[3]=0u;
                f32x4 cx=MF(a1,fbQ,bc0);
                aC[gt]=MF(a2.s8,bhc.s8,cx);
            }
        }
        short8 wFC; f32x4 fccC;
        if(lo<2){
            pk8 r;
            r.u[0]=f22bf(fccW[lo*16+4*g],   fccW[lo*16+4*g+1]);
            r.u[1]=f22bf(fccW[lo*16+4*g+2], fccW[lo*16+4*g+3]);
            r.u[2]=0u; r.u[3]=0u; wFC=r.s8;
        } else wFC=zero8();
        fccC=(g==0)? f32x4{fccb[0],fccb[1],0.f,0.f} : f32x4{0.f,0.f,0.f,0.f};
        short8 wCA[4]; f32x4 biasC[4];
#pragma unroll
        for(int gt=0;gt<4;++gt){
            int R=gt*16+lo;
            uint2 qc=*(const uint2*)&wsCh[R*16+4*g];
            pk8 rc; rc.u[0]=qc.x; rc.u[1]=qc.y;
            rc.u[2]=(g==0)? *(const unsigned*)&wsCp[R*2] : 0u; rc.u[3]=0u;
            wCA[gt]=rc.s8;
            biasC[gt]=*(const f32x4*)&wsBC[gt*16+4*g];
        }
#pragma unroll 1
        for(int s=0;s<PREDL;++s){
            pw4v(aC,cC,hcp0,hcp1);
            pk8 bhc2; bhc2.u[0]=hcp0; bhc2.u[1]=hcp1; bhc2.u[2]=0u; bhc2.u[3]=0u;
            f32x4 zz=MF(wFC,bhc2.s8,fccC);
            float z0=zz[0], z1=zz[1];
            float mx=fmaxf(z0,z1);
            float e0=EXP2(LOG2E*(z0-mx)), e1=EXP2(LOG2E*(z1-mx));
            float rs=RCP(e0+e1);
            float p0=e0*rs, p1=e1*rs;
            unsigned ppn=f22bf(p0,p1);
            if(g==0)
                ((float2*)out_cr)[(size_t)s*BATCH+pb+lo]=make_float2(p0,p1);
            pp=(unsigned)__shfl((int)ppn, lo, 64);
            if(s+1<PREDL){
                pk8 bc; bc.u[0]=hcp0; bc.u[1]=hcp1; bc.u[2]=(g==0)?pp:0u; bc.u[3]=0u;
#pragma unroll
                for(int gt=0;gt<4;++gt) aC[gt]=MF(wCA[gt],bc.s8,biasC[gt]);
            }
        }
    }
}

extern "C" void kernel_launch(void* const* d_in, const int* in_sizes, int n_in,
                              void* d_out, int out_size, void* d_ws, size_t ws_size,
                              hipStream_t stream)
{
    const float* obs  = (const float*)d_in[0];
    const float* eWih = (const float*)d_in[1];
    const float* eWhh = (const float*)d_in[2];
    const float* ebih = (const float*)d_in[3];
    const float* ebhh = (const float*)d_in[4];
    const float* dWih = (const float*)d_in[5];
    const float* dWhh = (const float*)d_in[6];
    const float* dbih = (const float*)d_in[7];
    const float* dbhh = (const float*)d_in[8];
    const float* cWih = (const float*)d_in[9];
    const float* cWhh = (const float*)d_in[10];
    const float* cbih = (const float*)d_in[11];
    const float* cbhh = (const float*)d_in[12];
    const float* fcW  = (const float*)d_in[13];
    const float* fcb  = (const float*)d_in[14];
    const float* fccW = (const float*)d_in[15];
    const float* fccb = (const float*)d_in[16];
    const float* mlpW = (const float*)d_in[17];
    const float* mlpb = (const float*)d_in[18];
    const float* embW = (const float*)d_in[19];
    const float* embb = (const float*)d_in[20];

    float* out_s  = (float*)d_out;
    float* out_cr = out_s + (size_t)PREDL*BATCH*POSE;

    float* wsBD = (float*)d_ws;                        // 64 f32
    float* wsBC = wsBD + 64;                           // 64 f32
    unsigned short* wsDh = (unsigned short*)(wsBC+64); // 1024 bf16
    unsigned short* wsCh = wsDh + 1024;                // 1024 bf16
    unsigned short* wsCp = wsCh + 1024;                // 128 bf16
    unsigned* hand = (unsigned*)((char*)d_ws + 8192);  // 2048*64*8 u32 = 4 MB

    hipLaunchKernelGGL(lstm_enc, dim3(513), dim3(256), 0, stream,
                       obs, eWih, eWhh, ebih, ebhh, mlpW, mlpb,
                       dWih, dWhh, dbih, dbhh, cWih, cWhh, cbih, cbhh,
                       fcW, fcb, embW, embb,
                       wsBD, wsBC, wsDh, wsCh, wsCp, hand);
    hipLaunchKernelGGL(lstm_dec, dim3(BATCH/32), dim3(256), 0, stream,
                       obs, dWih, dWhh, dbih, dbhh, cWih, cWhh, cbih, cbhh,
                       fcW, fcb, fccW, fccb,
                       wsBD, wsBC, wsDh, wsCh, wsCp, hand,
                       out_s, out_cr);
}